// Round 1
// baseline (45329.547 us; speedup 1.0000x reference)
//
#include <hip/hip_runtime.h>
#include <hip/hip_bf16.h>
#include <stdint.h>

// Problem constants
#define HD   1024
#define BB   32
#define TT   512
#define LL   3
#define H3   3072
#define MTOT (BB*TT)   // 16384

typedef unsigned short u16;
typedef short bf16x8 __attribute__((ext_vector_type(8)));
typedef float f32x4 __attribute__((ext_vector_type(4)));

__device__ __forceinline__ u16 f2bf_bits(float f) {
    __hip_bfloat16 h = __float2bfloat16(f);   // RNE
    return __builtin_bit_cast(u16, h);
}
__device__ __forceinline__ float bf_bits2f(u16 b) {
    return __bfloat162float(__builtin_bit_cast(__hip_bfloat16, b));
}

// ---------------------------------------------------------------------------
// Split fp32 -> (hi, lo) bf16 planes
__global__ void split_f32_kernel(const float* __restrict__ in,
                                 u16* __restrict__ hi, u16* __restrict__ lo, int n4) {
    int i = blockIdx.x * blockDim.x + threadIdx.x;
    int stride = gridDim.x * blockDim.x;
    for (; i < n4; i += stride) {
        float4 v = ((const float4*)in)[i];
        ushort4 h, l;
        float f;
        f = v.x; h.x = f2bf_bits(f); l.x = f2bf_bits(f - bf_bits2f(h.x));
        f = v.y; h.y = f2bf_bits(f); l.y = f2bf_bits(f - bf_bits2f(h.y));
        f = v.z; h.z = f2bf_bits(f); l.z = f2bf_bits(f - bf_bits2f(h.z));
        f = v.w; h.w = f2bf_bits(f); l.w = f2bf_bits(f - bf_bits2f(h.w));
        ((ushort4*)hi)[i] = h;
        ((ushort4*)lo)[i] = l;
    }
}

// fp32 -> bf16 (hi only)
__global__ void tobf_kernel(const float* __restrict__ in, u16* __restrict__ out, int n4) {
    int i = blockIdx.x * blockDim.x + threadIdx.x;
    int stride = gridDim.x * blockDim.x;
    for (; i < n4; i += stride) {
        float4 v = ((const float4*)in)[i];
        ushort4 h;
        h.x = f2bf_bits(v.x); h.y = f2bf_bits(v.y);
        h.z = f2bf_bits(v.z); h.w = f2bf_bits(v.w);
        ((ushort4*)out)[i] = h;
    }
}

// ---------------------------------------------------------------------------
// 2-pass split-A bf16 MFMA GEMM:  C[m][n] = sum_k (Ahi+Alo)[m][k] * W[n][k] + bias[n]
// M=16384 (x128 tiles), N=3072 (x24 tiles), K=1024. C stored bf16.
#define BM 128
#define BN 128
#define BK 32
#define LDSROW 40   // 32 data bf16 + 8 pad (80B row stride -> 2-way banks = free)

__global__ __launch_bounds__(256) void gemm2p_kernel(
    const u16* __restrict__ Ahi, const u16* __restrict__ Alo,  // [M][1024]
    const u16* __restrict__ Wn,                                 // [3072][1024]
    const float* __restrict__ bias,                             // [3072]
    u16* __restrict__ Cout)                                     // [M][3072]
{
    __shared__ u16 sAh[BM * LDSROW];
    __shared__ u16 sAl[BM * LDSROW];
    __shared__ u16 sB [BN * LDSROW];

    const int tid  = threadIdx.x;
    const int lane = tid & 63;
    const int w    = tid >> 6;        // 4 waves
    const int wr   = w >> 1, wc = w & 1;
    const int fr   = lane & 15;       // row within 16-tile (A: m, B: n)
    const int kg   = lane >> 4;       // k-group (8 bf16 each)

    const int bm = blockIdx.x & 127;         // M/BM = 128
    const int bn = blockIdx.x >> 7;          // N/BN = 24
    const int bmBase = bm * BM;
    const int bnBase = bn * BN;

    f32x4 acc[4][4] = {};

    for (int kt = 0; kt < 1024; kt += BK) {
        uint4 ra[2], rl[2], rb[2];
#pragma unroll
        for (int it = 0; it < 2; ++it) {
            int c = it * 256 + tid;          // 0..511
            int row = c >> 2, seg = c & 3;
            size_t ga = (size_t)(bmBase + row) * 1024 + kt + seg * 8;
            ra[it] = *(const uint4*)(Ahi + ga);
            rl[it] = *(const uint4*)(Alo + ga);
            size_t gb = (size_t)(bnBase + row) * 1024 + kt + seg * 8;
            rb[it] = *(const uint4*)(Wn + gb);
        }
        __syncthreads();   // previous iter's fragment reads complete
#pragma unroll
        for (int it = 0; it < 2; ++it) {
            int c = it * 256 + tid;
            int row = c >> 2, seg = c & 3;
            int lo = row * LDSROW + seg * 8;
            *(uint4*)(sAh + lo) = ra[it];
            *(uint4*)(sAl + lo) = rl[it];
            *(uint4*)(sB  + lo) = rb[it];
        }
        __syncthreads();

        bf16x8 fah[4], fal[4], fb[4];
#pragma unroll
        for (int mi = 0; mi < 4; ++mi) {
            int r = wr * 64 + mi * 16 + fr;
            fah[mi] = *(const bf16x8*)(sAh + r * LDSROW + kg * 8);
            fal[mi] = *(const bf16x8*)(sAl + r * LDSROW + kg * 8);
        }
#pragma unroll
        for (int ni = 0; ni < 4; ++ni) {
            int r = wc * 64 + ni * 16 + fr;
            fb[ni] = *(const bf16x8*)(sB + r * LDSROW + kg * 8);
        }
#pragma unroll
        for (int mi = 0; mi < 4; ++mi)
#pragma unroll
            for (int ni = 0; ni < 4; ++ni) {
                acc[mi][ni] = __builtin_amdgcn_mfma_f32_16x16x32_bf16(fah[mi], fb[ni], acc[mi][ni], 0, 0, 0);
                acc[mi][ni] = __builtin_amdgcn_mfma_f32_16x16x32_bf16(fal[mi], fb[ni], acc[mi][ni], 0, 0, 0);
            }
    }

    // Epilogue: C/D layout col = lane&15 (n), row = (lane>>4)*4 + reg (m)
#pragma unroll
    for (int mi = 0; mi < 4; ++mi)
#pragma unroll
        for (int ni = 0; ni < 4; ++ni) {
            int n = bnBase + wc * 64 + ni * 16 + fr;
            float bv = bias[n];
#pragma unroll
            for (int r = 0; r < 4; ++r) {
                int m = bmBase + wr * 64 + mi * 16 + kg * 4 + r;
                Cout[(size_t)m * H3 + n] = f2bf_bits(acc[mi][ni][r] + bv);
            }
        }
}

// ---------------------------------------------------------------------------
// Persistent recurrent kernel (one per layer): 512 steps with a software grid
// barrier. 256 blocks x 512 threads. Block owns 4 hidden units (12 w_hh rows,
// kept in registers: wave (rt,bh) holds rows rt*3..rt*3+2, 16 f32/lane each).
#define NBLK 256
#define UB 4

__global__ __launch_bounds__(512) void gru_rec_kernel(
    const float* __restrict__ whh,   // [3072][1024] (this layer)
    const float* __restrict__ bhh,   // [3072]
    const u16*  __restrict__ gi,     // [B*T][3072] bf16 (includes b_ih)
    const float* __restrict__ h0,    // [B][H] (this layer)
    float* __restrict__ hbuf0, float* __restrict__ hbuf1,  // [B][H] state ping-pong
    u16*  __restrict__ phi, u16* __restrict__ plo,         // next-layer planes or null
    float* __restrict__ seqout,                            // fp32 [B][T][H] or null
    float* __restrict__ hnout,                             // [B][H]
    unsigned* __restrict__ cnt)
{
    const int tid  = threadIdx.x;
    const int lane = tid & 63;
    const int w    = tid >> 6;     // 8 waves
    const int bh   = w >> 2;       // batch half
    const int rt   = w & 3;        // row trio
    const int u0   = blockIdx.x * UB;

    __shared__ float dsm[12][BB][16];   // 24KB partials
    __shared__ float bsh[12];

    // Load this wave's 3 w_hh rows into registers (16 f32 per lane per row).
    float wreg[3][16];
#pragma unroll
    for (int j = 0; j < 3; ++j) {
        int i = rt * 3 + j;
        int g = i >> 2, u = i & 3;
        const float* wp = whh + (size_t)(g * HD + u0 + u) * HD;
#pragma unroll
        for (int j4 = 0; j4 < 4; ++j4) {
            float4 v = *(const float4*)(wp + j4 * 256 + lane * 4);
            wreg[j][j4 * 4 + 0] = v.x; wreg[j][j4 * 4 + 1] = v.y;
            wreg[j][j4 * 4 + 2] = v.z; wreg[j][j4 * 4 + 3] = v.w;
        }
    }
    if (tid < 12) {
        int g = tid >> 2, u = tid & 3;
        bsh[tid] = bhh[g * HD + u0 + u];
    }
    __syncthreads();

    for (int t = 0; t < TT; ++t) {
        const float* hsrc = (t == 0) ? h0 : ((t & 1) ? hbuf1 : hbuf0);
        float* hdst = ((t + 1) & 1) ? hbuf1 : hbuf0;

        // ---- dot phase: gh partials for 3 rows x 16 batches per wave
        for (int bb = 0; bb < 16; ++bb) {
            int b = bh * 16 + bb;
            const float* hrow = hsrc + b * HD;
            float a0 = 0.f, a1 = 0.f, a2 = 0.f;
#pragma unroll
            for (int j4 = 0; j4 < 4; ++j4) {
                float4 hv = *(const float4*)(hrow + j4 * 256 + lane * 4);
#pragma unroll
                for (int e = 0; e < 4; ++e) {
                    float hx = (&hv.x)[e];
                    a0 = fmaf(wreg[0][j4 * 4 + e], hx, a0);
                    a1 = fmaf(wreg[1][j4 * 4 + e], hx, a1);
                    a2 = fmaf(wreg[2][j4 * 4 + e], hx, a2);
                }
            }
            a0 += __shfl_xor(a0, 1); a0 += __shfl_xor(a0, 2);
            a1 += __shfl_xor(a1, 1); a1 += __shfl_xor(a1, 2);
            a2 += __shfl_xor(a2, 1); a2 += __shfl_xor(a2, 2);
            if ((lane & 3) == 0) {
                int p = lane >> 2;
                dsm[rt * 3 + 0][b][p] = a0;
                dsm[rt * 3 + 1][b][p] = a1;
                dsm[rt * 3 + 2][b][p] = a2;
            }
        }
        __syncthreads();

        // ---- gate phase: 128 threads, one (b, u) each
        if (tid < 128) {
            int b = tid >> 2, u = tid & 3;
            float dr = 0.f, dz = 0.f, dn = 0.f;
#pragma unroll
            for (int p = 0; p < 16; ++p) {
                dr += dsm[u][b][p];
                dz += dsm[4 + u][b][p];
                dn += dsm[8 + u][b][p];
            }
            dr += bsh[u]; dz += bsh[4 + u]; dn += bsh[8 + u];
            int n = u0 + u;
            size_t mrow = (size_t)b * TT + t;
            float ir  = bf_bits2f(gi[mrow * H3 + n]);
            float iz  = bf_bits2f(gi[mrow * H3 + HD + n]);
            float inn = bf_bits2f(gi[mrow * H3 + 2 * HD + n]);
            float hp = hsrc[b * HD + n];
            float r = 1.f / (1.f + expf(-(ir + dr)));
            float z = 1.f / (1.f + expf(-(iz + dz)));
            float nn = tanhf(inn + r * dn);
            float hnew = (1.f - z) * nn + z * hp;
            hdst[b * HD + n] = hnew;
            if (seqout) {
                seqout[mrow * HD + n] = hnew;
            } else {
                u16 hb_ = f2bf_bits(hnew);
                phi[mrow * HD + n] = hb_;
                plo[mrow * HD + n] = f2bf_bits(hnew - bf_bits2f(hb_));
            }
            if (t == TT - 1) hnout[b * HD + n] = hnew;
        }

        // ---- grid barrier (skip after last step)
        if (t < TT - 1) {
            __syncthreads();
            if (tid == 0) {
                __threadfence();               // flush this block's writes
                atomicAdd(cnt, 1u);
                unsigned tgt = (unsigned)NBLK * (unsigned)(t + 1);
                while (__hip_atomic_load(cnt, __ATOMIC_ACQUIRE, __HIP_MEMORY_SCOPE_AGENT) < tgt) {
                    __builtin_amdgcn_s_sleep(2);
                }
                __threadfence();               // invalidate stale cached h
            }
            __syncthreads();
        }
    }
}

// ---------------------------------------------------------------------------
extern "C" void kernel_launch(void* const* d_in, const int* in_sizes, int n_in,
                              void* d_out, int out_size, void* d_ws, size_t ws_size,
                              hipStream_t stream) {
    const float* x   = (const float*)d_in[0];   // [B][T][H]
    const float* h0  = (const float*)d_in[1];   // [L][B][H]
    const float* wih = (const float*)d_in[2];   // [L][3H][H]
    const float* whh = (const float*)d_in[3];   // [L][3H][H]
    const float* bih = (const float*)d_in[4];   // [L][3H]
    const float* bhh = (const float*)d_in[5];   // [L][3H]
    float* out = (float*)d_out;

    char* ws = (char*)d_ws;
    size_t off = 0;
    auto alloc = [&](size_t bytes) -> void* {
        void* p = ws + off;
        off += (bytes + 255) & ~(size_t)255;
        return p;
    };
    u16* gi   = (u16*)alloc((size_t)MTOT * H3 * 2);        // 96 MB
    u16* p0h  = (u16*)alloc((size_t)MTOT * HD * 2);        // 32 MB
    u16* p0l  = (u16*)alloc((size_t)MTOT * HD * 2);
    u16* p1h  = (u16*)alloc((size_t)MTOT * HD * 2);
    u16* p1l  = (u16*)alloc((size_t)MTOT * HD * 2);
    u16* wihb = (u16*)alloc((size_t)LL * H3 * HD * 2);     // 18 MB
    float* hb0 = (float*)alloc((size_t)BB * HD * 4);
    float* hb1 = (float*)alloc((size_t)BB * HD * 4);
    unsigned* cnt = (unsigned*)alloc(256);

    hipMemsetAsync(cnt, 0, 256, stream);

    // converts
    split_f32_kernel<<<2048, 256, 0, stream>>>(x, p0h, p0l, MTOT * HD / 4);
    tobf_kernel<<<2048, 256, 0, stream>>>(wih, wihb, LL * H3 * HD / 4);

    float* seqbase = out;                        // [B][T][H]
    float* hnbase  = out + (size_t)BB * TT * HD; // [L][B][H]

    for (int l = 0; l < LL; ++l) {
        const u16* ah = (l == 1) ? p1h : p0h;    // l0: p0(x), l1: p1, l2: p0
        const u16* al = (l == 1) ? p1l : p0l;
        gemm2p_kernel<<<dim3(128 * 24), 256, 0, stream>>>(
            ah, al, wihb + (size_t)l * H3 * HD, bih + (size_t)l * H3, gi);

        u16* oh = (l == 0) ? p1h : p0h;          // l0 writes p1, l1 writes p0
        u16* ol = (l == 0) ? p1l : p0l;
        gru_rec_kernel<<<NBLK, 512, 0, stream>>>(
            whh + (size_t)l * H3 * HD, bhh + (size_t)l * H3, gi,
            h0 + (size_t)l * BB * HD, hb0, hb1,
            (l < 2) ? oh : (u16*)nullptr, (l < 2) ? ol : (u16*)nullptr,
            (l == 2) ? seqbase : (float*)nullptr,
            hnbase + (size_t)l * BB * HD,
            cnt + (size_t)l * 16);
    }
}

// Round 2
// 24923.692 us; speedup vs baseline: 1.8187x; 1.8187x over previous
//
#include <hip/hip_runtime.h>
#include <hip/hip_bf16.h>
#include <stdint.h>

// Problem constants
#define HD   1024
#define BB   32
#define TT   512
#define LL   3
#define H3   3072
#define MTOT (BB*TT)   // 16384

typedef unsigned short u16;
typedef short bf16x8 __attribute__((ext_vector_type(8)));
typedef float f32x4 __attribute__((ext_vector_type(4)));

__device__ __forceinline__ u16 f2bf_bits(float f) {
    __hip_bfloat16 h = __float2bfloat16(f);   // RNE
    return __builtin_bit_cast(u16, h);
}
__device__ __forceinline__ float bf_bits2f(u16 b) {
    return __bfloat162float(__builtin_bit_cast(__hip_bfloat16, b));
}

// ---- coherent (IC-level, cross-XCD) access helpers: sc0 sc1 = system scope,
// bypasses L1 and the per-XCD L2 so no cache-wide invalidate fences are needed.
__device__ __forceinline__ void coh_load_f4(f32x4& d, const float* p) {
    asm volatile("global_load_dwordx4 %0, %1, off sc0 sc1" : "=v"(d) : "v"(p));
}
__device__ __forceinline__ void coh_store_f32(float* p, float v) {
    asm volatile("global_store_dword %0, %1, off sc0 sc1" : : "v"(p), "v"(v) : "memory");
}
__device__ __forceinline__ void ld_u16_async(unsigned& d, const u16* p) {
    asm volatile("global_load_ushort %0, %1, off" : "=v"(d) : "v"(p));
}
// sum of the 8 spread arrival counters (coherent loads, single waitcnt; results
// tied through the waitcnt asm so nothing can be hoisted past it)
__device__ __forceinline__ unsigned cnt_sum8(const unsigned* c) {
    unsigned v0,v1,v2,v3,v4,v5,v6,v7;
    asm volatile("global_load_dword %0, %1, off sc0 sc1" : "=v"(v0) : "v"(c + 0*64));
    asm volatile("global_load_dword %0, %1, off sc0 sc1" : "=v"(v1) : "v"(c + 1*64));
    asm volatile("global_load_dword %0, %1, off sc0 sc1" : "=v"(v2) : "v"(c + 2*64));
    asm volatile("global_load_dword %0, %1, off sc0 sc1" : "=v"(v3) : "v"(c + 3*64));
    asm volatile("global_load_dword %0, %1, off sc0 sc1" : "=v"(v4) : "v"(c + 4*64));
    asm volatile("global_load_dword %0, %1, off sc0 sc1" : "=v"(v5) : "v"(c + 5*64));
    asm volatile("global_load_dword %0, %1, off sc0 sc1" : "=v"(v6) : "v"(c + 6*64));
    asm volatile("global_load_dword %0, %1, off sc0 sc1" : "=v"(v7) : "v"(c + 7*64));
    asm volatile("s_waitcnt vmcnt(0)"
                 : "+v"(v0),"+v"(v1),"+v"(v2),"+v"(v3),
                   "+v"(v4),"+v"(v5),"+v"(v6),"+v"(v7));
    return ((v0+v1)+(v2+v3))+((v4+v5)+(v6+v7));
}

// ---------------------------------------------------------------------------
// Split fp32 -> (hi, lo) bf16 planes
__global__ void split_f32_kernel(const float* __restrict__ in,
                                 u16* __restrict__ hi, u16* __restrict__ lo, int n4) {
    int i = blockIdx.x * blockDim.x + threadIdx.x;
    int stride = gridDim.x * blockDim.x;
    for (; i < n4; i += stride) {
        float4 v = ((const float4*)in)[i];
        ushort4 h, l;
        float f;
        f = v.x; h.x = f2bf_bits(f); l.x = f2bf_bits(f - bf_bits2f(h.x));
        f = v.y; h.y = f2bf_bits(f); l.y = f2bf_bits(f - bf_bits2f(h.y));
        f = v.z; h.z = f2bf_bits(f); l.z = f2bf_bits(f - bf_bits2f(h.z));
        f = v.w; h.w = f2bf_bits(f); l.w = f2bf_bits(f - bf_bits2f(h.w));
        ((ushort4*)hi)[i] = h;
        ((ushort4*)lo)[i] = l;
    }
}

// fp32 -> bf16 (hi only)
__global__ void tobf_kernel(const float* __restrict__ in, u16* __restrict__ out, int n4) {
    int i = blockIdx.x * blockDim.x + threadIdx.x;
    int stride = gridDim.x * blockDim.x;
    for (; i < n4; i += stride) {
        float4 v = ((const float4*)in)[i];
        ushort4 h;
        h.x = f2bf_bits(v.x); h.y = f2bf_bits(v.y);
        h.z = f2bf_bits(v.z); h.w = f2bf_bits(v.w);
        ((ushort4*)out)[i] = h;
    }
}

// ---------------------------------------------------------------------------
// 2-pass split-A bf16 MFMA GEMM:  C[t*32+b][n] = sum_k (Ahi+Alo)[b*512+t][k]*W[n][k] + bias[n]
// Output rows are PERMUTED to [t][b] so the recurrent kernel's per-step reads
// are contiguous. M=16384, N=3072, K=1024.
#define BM 128
#define BN 128
#define BK 32
#define LDSROW 40   // 32 data bf16 + 8 pad

__global__ __launch_bounds__(256) void gemm2p_kernel(
    const u16* __restrict__ Ahi, const u16* __restrict__ Alo,  // [M][1024]
    const u16* __restrict__ Wn,                                 // [3072][1024]
    const float* __restrict__ bias,                             // [3072]
    u16* __restrict__ Cout)                                     // [T*B perm][3072]
{
    __shared__ u16 sAh[BM * LDSROW];
    __shared__ u16 sAl[BM * LDSROW];
    __shared__ u16 sB [BN * LDSROW];

    const int tid  = threadIdx.x;
    const int lane = tid & 63;
    const int w    = tid >> 6;        // 4 waves
    const int wr   = w >> 1, wc = w & 1;
    const int fr   = lane & 15;
    const int kg   = lane >> 4;

    const int bm = blockIdx.x & 127;         // M/BM = 128
    const int bn = blockIdx.x >> 7;          // N/BN = 24
    const int bmBase = bm * BM;
    const int bnBase = bn * BN;

    f32x4 acc[4][4] = {};

    for (int kt = 0; kt < 1024; kt += BK) {
        uint4 ra[2], rl[2], rb[2];
#pragma unroll
        for (int it = 0; it < 2; ++it) {
            int c = it * 256 + tid;
            int row = c >> 2, seg = c & 3;
            size_t ga = (size_t)(bmBase + row) * 1024 + kt + seg * 8;
            ra[it] = *(const uint4*)(Ahi + ga);
            rl[it] = *(const uint4*)(Alo + ga);
            size_t gb = (size_t)(bnBase + row) * 1024 + kt + seg * 8;
            rb[it] = *(const uint4*)(Wn + gb);
        }
        __syncthreads();
#pragma unroll
        for (int it = 0; it < 2; ++it) {
            int c = it * 256 + tid;
            int row = c >> 2, seg = c & 3;
            int lo = row * LDSROW + seg * 8;
            *(uint4*)(sAh + lo) = ra[it];
            *(uint4*)(sAl + lo) = rl[it];
            *(uint4*)(sB  + lo) = rb[it];
        }
        __syncthreads();

        bf16x8 fah[4], fal[4], fb[4];
#pragma unroll
        for (int mi = 0; mi < 4; ++mi) {
            int r = wr * 64 + mi * 16 + fr;
            fah[mi] = *(const bf16x8*)(sAh + r * LDSROW + kg * 8);
            fal[mi] = *(const bf16x8*)(sAl + r * LDSROW + kg * 8);
        }
#pragma unroll
        for (int ni = 0; ni < 4; ++ni) {
            int r = wc * 64 + ni * 16 + fr;
            fb[ni] = *(const bf16x8*)(sB + r * LDSROW + kg * 8);
        }
#pragma unroll
        for (int mi = 0; mi < 4; ++mi)
#pragma unroll
            for (int ni = 0; ni < 4; ++ni) {
                acc[mi][ni] = __builtin_amdgcn_mfma_f32_16x16x32_bf16(fah[mi], fb[ni], acc[mi][ni], 0, 0, 0);
                acc[mi][ni] = __builtin_amdgcn_mfma_f32_16x16x32_bf16(fal[mi], fb[ni], acc[mi][ni], 0, 0, 0);
            }
    }

#pragma unroll
    for (int mi = 0; mi < 4; ++mi)
#pragma unroll
        for (int ni = 0; ni < 4; ++ni) {
            int n = bnBase + wc * 64 + ni * 16 + fr;
            float bv = bias[n];
#pragma unroll
            for (int r = 0; r < 4; ++r) {
                int m = bmBase + wr * 64 + mi * 16 + kg * 4 + r;
                int b_ = m >> 9, t_ = m & 511;           // m = b*512 + t
                Cout[(size_t)(t_ * BB + b_) * H3 + n] = f2bf_bits(acc[mi][ni][r] + bv);
            }
        }
}

// ---------------------------------------------------------------------------
// Persistent recurrent kernel: 256 blocks (64 unit-groups x 4 batch-groups) x
// 512 threads. Block owns 16 units x 8 batches. w_hh rows in registers.
// Cross-step sync: 8 spread monotonic counters + coherent (sc0 sc1) h exchange.
#define RGRID 256

__global__ __launch_bounds__(512) void gru_rec_kernel(
    const float* __restrict__ whh,   // [3072][1024] this layer
    const float* __restrict__ bhh,   // [3072]
    const u16*  __restrict__ gi,     // [T][B][3H] bf16, includes b_ih
    const float* __restrict__ h0,    // [B][H] this layer
    float* __restrict__ hbuf0, float* __restrict__ hbuf1,
    u16*  __restrict__ phi, u16* __restrict__ plo,   // next-layer planes or null
    float* __restrict__ seqout,                      // fp32 [B][T][H] or null
    float* __restrict__ hnout,                       // [B][H]
    unsigned* __restrict__ cnt)                      // 8 counters, 256B apart
{
    const int tid  = threadIdx.x;
    const int lane = tid & 63;
    const int w    = tid >> 6;           // 8 waves = 8 row-groups of 6
    const int ug   = blockIdx.x >> 2;    // 0..63
    const int bg   = blockIdx.x & 3;     // 0..3
    const int u0   = ug * 16;
    const int b0   = bg * 8;

    __shared__ __align__(16) float h_lds[8 * HD];        // 32 KB: this block's 8 h rows
    __shared__ __align__(16) float dsm[8 * 48 * 4];      // 6 KB partials
    __shared__ float bsh[48];

    // weights: wave w holds block-rows w*6..w*6+5; lane's K-slice = {q*256 + lane*4 + e}
    float wreg[6][16];
#pragma unroll
    for (int j = 0; j < 6; ++j) {
        int r = w * 6 + j;
        int g = r >> 4, uu = r & 15;
        const float* wp = whh + (size_t)(g * HD + u0 + uu) * HD;
#pragma unroll
        for (int q = 0; q < 4; ++q) {
            f32x4 v = *(const f32x4*)(wp + q * 256 + lane * 4);
            wreg[j][q * 4 + 0] = v[0]; wreg[j][q * 4 + 1] = v[1];
            wreg[j][q * 4 + 2] = v[2]; wreg[j][q * 4 + 3] = v[3];
        }
    }
    if (tid < 48) bsh[tid] = bhh[(tid >> 4) * HD + u0 + (tid & 15)];
    __syncthreads();

    const int gb = tid >> 4;    // gate-phase batch (tid<128)
    const int gu = tid & 15;    // gate-phase unit

    for (int t = 0; t < TT; ++t) {
        // ---- gi prefetch (independent of h; in flight during the spin)
        unsigned gr0, gr1, gr2;
        if (tid < 128) {
            const u16* gp = gi + (size_t)(t * BB + b0 + gb) * H3 + u0 + gu;
            ld_u16_async(gr0, gp);
            ld_u16_async(gr1, gp + HD);
            ld_u16_async(gr2, gp + 2 * HD);
        }
        // ---- wait for all blocks to finish step t-1
        if (t > 0) {
            unsigned tgt = (unsigned)(RGRID * t);
            while (cnt_sum8(cnt) < tgt) __builtin_amdgcn_s_sleep(1);
        }
        // ---- stage h(t) for our 8 batches into LDS (coherent loads)
        const float* hsrc = (t == 0) ? (h0 + b0 * HD)
                                     : (((t & 1) ? hbuf1 : hbuf0) + b0 * HD);
        f32x4 s0_, s1_, s2_, s3_;
        coh_load_f4(s0_, hsrc + (0 * 512 + tid) * 4);
        coh_load_f4(s1_, hsrc + (1 * 512 + tid) * 4);
        coh_load_f4(s2_, hsrc + (2 * 512 + tid) * 4);
        coh_load_f4(s3_, hsrc + (3 * 512 + tid) * 4);
        asm volatile("s_waitcnt vmcnt(0)" : "+v"(s0_), "+v"(s1_), "+v"(s2_), "+v"(s3_));
        *(f32x4*)&h_lds[(0 * 512 + tid) * 4] = s0_;
        *(f32x4*)&h_lds[(1 * 512 + tid) * 4] = s1_;
        *(f32x4*)&h_lds[(2 * 512 + tid) * 4] = s2_;
        *(f32x4*)&h_lds[(3 * 512 + tid) * 4] = s3_;
        __syncthreads();

        // ---- dot phase: 6 rows x 8 batches per wave, 16 K-elems per lane
#pragma unroll 2
        for (int b = 0; b < 8; ++b) {
            const float* hr = h_lds + b * HD;
            f32x4 h0v = *(const f32x4*)(hr + 0 * 256 + lane * 4);
            f32x4 h1v = *(const f32x4*)(hr + 1 * 256 + lane * 4);
            f32x4 h2v = *(const f32x4*)(hr + 2 * 256 + lane * 4);
            f32x4 h3v = *(const f32x4*)(hr + 3 * 256 + lane * 4);
#pragma unroll
            for (int j = 0; j < 6; ++j) {
                float a = 0.f;
#pragma unroll
                for (int e = 0; e < 4; ++e) {
                    a = fmaf(wreg[j][e],      h0v[e], a);
                    a = fmaf(wreg[j][4 + e],  h1v[e], a);
                    a = fmaf(wreg[j][8 + e],  h2v[e], a);
                    a = fmaf(wreg[j][12 + e], h3v[e], a);
                }
                a += __shfl_xor(a, 1);
                a += __shfl_xor(a, 2);
                a += __shfl_xor(a, 4);
                a += __shfl_xor(a, 8);
                if ((lane & 15) == 0)
                    dsm[(b * 48 + w * 6 + j) * 4 + (lane >> 4)] = a;
            }
        }
        __syncthreads();

        // ---- gate phase: 128 threads, one (b,u) each
        float* hdst = ((t + 1) & 1) ? hbuf1 : hbuf0;
        if (tid < 128) {
            f32x4 p0 = *(const f32x4*)&dsm[(gb * 48 + 0 * 16 + gu) * 4];
            f32x4 p1 = *(const f32x4*)&dsm[(gb * 48 + 1 * 16 + gu) * 4];
            f32x4 p2 = *(const f32x4*)&dsm[(gb * 48 + 2 * 16 + gu) * 4];
            float dr = p0[0] + p0[1] + p0[2] + p0[3] + bsh[gu];
            float dz = p1[0] + p1[1] + p1[2] + p1[3] + bsh[16 + gu];
            float dn = p2[0] + p2[1] + p2[2] + p2[3] + bsh[32 + gu];
            float ir  = bf_bits2f((u16)gr0);
            float iz  = bf_bits2f((u16)gr1);
            float inn = bf_bits2f((u16)gr2);
            float hp = h_lds[gb * HD + u0 + gu];
            float r = 1.f / (1.f + expf(-(ir + dr)));
            float z = 1.f / (1.f + expf(-(iz + dz)));
            float nn = tanhf(inn + r * dn);
            float hnew = (1.f - z) * nn + z * hp;
            int gidx = (b0 + gb) * HD + u0 + gu;
            coh_store_f32(hdst + gidx, hnew);
            size_t orow = ((size_t)(b0 + gb) * TT + t) * HD + u0 + gu;
            if (seqout) {
                seqout[orow] = hnew;
            } else {
                u16 hb_ = f2bf_bits(hnew);
                phi[orow] = hb_;
                plo[orow] = f2bf_bits(hnew - bf_bits2f(hb_));
            }
            if (t == TT - 1) hnout[gidx] = hnew;
            asm volatile("s_waitcnt vmcnt(0)" ::: "memory");  // drain coherent stores
        }
        __syncthreads();   // all waves: stores drained before arrival
        if (t < TT - 1 && tid == 0)
            atomicAdd(cnt + (size_t)(blockIdx.x & 7) * 64, 1u);
    }
}

// ---------------------------------------------------------------------------
extern "C" void kernel_launch(void* const* d_in, const int* in_sizes, int n_in,
                              void* d_out, int out_size, void* d_ws, size_t ws_size,
                              hipStream_t stream) {
    const float* x   = (const float*)d_in[0];
    const float* h0  = (const float*)d_in[1];
    const float* wih = (const float*)d_in[2];
    const float* whh = (const float*)d_in[3];
    const float* bih = (const float*)d_in[4];
    const float* bhh = (const float*)d_in[5];
    float* out = (float*)d_out;

    char* ws = (char*)d_ws;
    size_t off = 0;
    auto alloc = [&](size_t bytes) -> void* {
        void* p = ws + off;
        off += (bytes + 255) & ~(size_t)255;
        return p;
    };
    u16* gi   = (u16*)alloc((size_t)MTOT * H3 * 2);        // 96 MB
    u16* p0h  = (u16*)alloc((size_t)MTOT * HD * 2);        // 32 MB
    u16* p0l  = (u16*)alloc((size_t)MTOT * HD * 2);
    u16* p1h  = (u16*)alloc((size_t)MTOT * HD * 2);
    u16* p1l  = (u16*)alloc((size_t)MTOT * HD * 2);
    u16* wihb = (u16*)alloc((size_t)LL * H3 * HD * 2);     // 18 MB
    float* hb0 = (float*)alloc((size_t)BB * HD * 4);
    float* hb1 = (float*)alloc((size_t)BB * HD * 4);
    unsigned* cnt = (unsigned*)alloc(3 * 2048);            // 8 counters/layer, 256B apart

    hipMemsetAsync(cnt, 0, 3 * 2048, stream);

    split_f32_kernel<<<2048, 256, 0, stream>>>(x, p0h, p0l, MTOT * HD / 4);
    tobf_kernel<<<2048, 256, 0, stream>>>(wih, wihb, LL * H3 * HD / 4);

    float* seqbase = out;                        // [B][T][H]
    float* hnbase  = out + (size_t)BB * TT * HD; // [L][B][H]

    for (int l = 0; l < LL; ++l) {
        const u16* ah = (l == 1) ? p1h : p0h;
        const u16* al = (l == 1) ? p1l : p0l;
        gemm2p_kernel<<<dim3(128 * 24), 256, 0, stream>>>(
            ah, al, wihb + (size_t)l * H3 * HD, bih + (size_t)l * H3, gi);

        u16* oh = (l == 0) ? p1h : p0h;
        u16* ol = (l == 0) ? p1l : p0l;
        gru_rec_kernel<<<RGRID, 512, 0, stream>>>(
            whh + (size_t)l * H3 * HD, bhh + (size_t)l * H3, gi,
            h0 + (size_t)l * BB * HD, hb0, hb1,
            (l < 2) ? oh : (u16*)nullptr, (l < 2) ? ol : (u16*)nullptr,
            (l == 2) ? seqbase : (float*)nullptr,
            hnbase + (size_t)l * BB * HD,
            cnt + (size_t)l * 512);
    }
}

// Round 3
// 21614.267 us; speedup vs baseline: 2.0972x; 1.1531x over previous
//
#include <hip/hip_runtime.h>
#include <hip/hip_bf16.h>
#include <stdint.h>

// Problem constants
#define HD   1024
#define BB   32
#define TT   512
#define LL   3
#define H3   3072
#define MTOT (BB*TT)   // 16384

typedef unsigned short u16;
typedef short bf16x8 __attribute__((ext_vector_type(8)));
typedef float f32x4 __attribute__((ext_vector_type(4)));

__device__ __forceinline__ u16 f2bf_bits(float f) {
    __hip_bfloat16 h = __float2bfloat16(f);   // RNE
    return __builtin_bit_cast(u16, h);
}
__device__ __forceinline__ float bf_bits2f(u16 b) {
    return __bfloat162float(__builtin_bit_cast(__hip_bfloat16, b));
}

// ---- coherent (IC-level, cross-XCD) access: sc0 sc1 = system scope, bypasses
// L1 and per-XCD L2 -> no cache-wide invalidates needed, ~IC latency.
__device__ __forceinline__ void coh_load_f4(f32x4& d, const float* p) {
    asm volatile("global_load_dwordx4 %0, %1, off sc0 sc1" : "=v"(d) : "v"(p));
}
__device__ __forceinline__ void coh_store_f32(float* p, float v) {
    asm volatile("global_store_dword %0, %1, off sc0 sc1" : : "v"(p), "v"(v) : "memory");
}
__device__ __forceinline__ void coh_store_u32(unsigned* p, unsigned v) {
    asm volatile("global_store_dword %0, %1, off sc0 sc1" : : "v"(p), "v"(v) : "memory");
}
__device__ __forceinline__ unsigned coh_load_u32_wait(const unsigned* p) {
    unsigned v;
    asm volatile("global_load_dword %0, %1, off sc0 sc1" : "=v"(v) : "v"(p));
    asm volatile("s_waitcnt vmcnt(0)" : "+v"(v));
    return v;
}
__device__ __forceinline__ void ld_u16_async(unsigned& d, const u16* p) {
    asm volatile("global_load_ushort %0, %1, off" : "=v"(d) : "v"(p));
}

// ---------------------------------------------------------------------------
// Split fp32 -> (hi, lo) bf16 planes
__global__ void split_f32_kernel(const float* __restrict__ in,
                                 u16* __restrict__ hi, u16* __restrict__ lo, int n4) {
    int i = blockIdx.x * blockDim.x + threadIdx.x;
    int stride = gridDim.x * blockDim.x;
    for (; i < n4; i += stride) {
        float4 v = ((const float4*)in)[i];
        ushort4 h, l;
        float f;
        f = v.x; h.x = f2bf_bits(f); l.x = f2bf_bits(f - bf_bits2f(h.x));
        f = v.y; h.y = f2bf_bits(f); l.y = f2bf_bits(f - bf_bits2f(h.y));
        f = v.z; h.z = f2bf_bits(f); l.z = f2bf_bits(f - bf_bits2f(h.z));
        f = v.w; h.w = f2bf_bits(f); l.w = f2bf_bits(f - bf_bits2f(h.w));
        ((ushort4*)hi)[i] = h;
        ((ushort4*)lo)[i] = l;
    }
}

// fp32 -> bf16 (hi only)
__global__ void tobf_kernel(const float* __restrict__ in, u16* __restrict__ out, int n4) {
    int i = blockIdx.x * blockDim.x + threadIdx.x;
    int stride = gridDim.x * blockDim.x;
    for (; i < n4; i += stride) {
        float4 v = ((const float4*)in)[i];
        ushort4 h;
        h.x = f2bf_bits(v.x); h.y = f2bf_bits(v.y);
        h.z = f2bf_bits(v.z); h.w = f2bf_bits(v.w);
        ((ushort4*)out)[i] = h;
    }
}

// ---------------------------------------------------------------------------
// 2-pass split-A bf16 MFMA GEMM:  C[t*32+b][n] = sum_k (Ahi+Alo)[b*512+t][k]*W[n][k] + bias[n]
#define BM 128
#define BN 128
#define BK 32
#define LDSROW 40   // 32 data bf16 + 8 pad

__global__ __launch_bounds__(256) void gemm2p_kernel(
    const u16* __restrict__ Ahi, const u16* __restrict__ Alo,  // [M][1024]
    const u16* __restrict__ Wn,                                 // [3072][1024]
    const float* __restrict__ bias,                             // [3072]
    u16* __restrict__ Cout)                                     // [T*B perm][3072]
{
    __shared__ u16 sAh[BM * LDSROW];
    __shared__ u16 sAl[BM * LDSROW];
    __shared__ u16 sB [BN * LDSROW];

    const int tid  = threadIdx.x;
    const int lane = tid & 63;
    const int w    = tid >> 6;        // 4 waves
    const int wr   = w >> 1, wc = w & 1;
    const int fr   = lane & 15;
    const int kg   = lane >> 4;

    const int bm = blockIdx.x & 127;         // M/BM = 128
    const int bn = blockIdx.x >> 7;          // N/BN = 24
    const int bmBase = bm * BM;
    const int bnBase = bn * BN;

    f32x4 acc[4][4] = {};

    for (int kt = 0; kt < 1024; kt += BK) {
        uint4 ra[2], rl[2], rb[2];
#pragma unroll
        for (int it = 0; it < 2; ++it) {
            int c = it * 256 + tid;
            int row = c >> 2, seg = c & 3;
            size_t ga = (size_t)(bmBase + row) * 1024 + kt + seg * 8;
            ra[it] = *(const uint4*)(Ahi + ga);
            rl[it] = *(const uint4*)(Alo + ga);
            size_t gb = (size_t)(bnBase + row) * 1024 + kt + seg * 8;
            rb[it] = *(const uint4*)(Wn + gb);
        }
        __syncthreads();
#pragma unroll
        for (int it = 0; it < 2; ++it) {
            int c = it * 256 + tid;
            int row = c >> 2, seg = c & 3;
            int lo = row * LDSROW + seg * 8;
            *(uint4*)(sAh + lo) = ra[it];
            *(uint4*)(sAl + lo) = rl[it];
            *(uint4*)(sB  + lo) = rb[it];
        }
        __syncthreads();

        bf16x8 fah[4], fal[4], fb[4];
#pragma unroll
        for (int mi = 0; mi < 4; ++mi) {
            int r = wr * 64 + mi * 16 + fr;
            fah[mi] = *(const bf16x8*)(sAh + r * LDSROW + kg * 8);
            fal[mi] = *(const bf16x8*)(sAl + r * LDSROW + kg * 8);
        }
#pragma unroll
        for (int ni = 0; ni < 4; ++ni) {
            int r = wc * 64 + ni * 16 + fr;
            fb[ni] = *(const bf16x8*)(sB + r * LDSROW + kg * 8);
        }
#pragma unroll
        for (int mi = 0; mi < 4; ++mi)
#pragma unroll
            for (int ni = 0; ni < 4; ++ni) {
                acc[mi][ni] = __builtin_amdgcn_mfma_f32_16x16x32_bf16(fah[mi], fb[ni], acc[mi][ni], 0, 0, 0);
                acc[mi][ni] = __builtin_amdgcn_mfma_f32_16x16x32_bf16(fal[mi], fb[ni], acc[mi][ni], 0, 0, 0);
            }
    }

#pragma unroll
    for (int mi = 0; mi < 4; ++mi)
#pragma unroll
        for (int ni = 0; ni < 4; ++ni) {
            int n = bnBase + wc * 64 + ni * 16 + fr;
            float bv = bias[n];
#pragma unroll
            for (int r = 0; r < 4; ++r) {
                int m = bmBase + wr * 64 + mi * 16 + kg * 4 + r;
                int b_ = m >> 9, t_ = m & 511;           // m = b*512 + t
                Cout[(size_t)(t_ * BB + b_) * H3 + n] = f2bf_bits(acc[mi][ni][r] + bv);
            }
        }
}

// ---------------------------------------------------------------------------
// Persistent recurrent kernel: 256 blocks (64 unit-groups x 4 batch-groups) x
// 512 threads. Block owns 16 units x 8 batches; w_hh rows in registers.
// Sync: per-bg flag vector (64 producer flags); ONE wave polls per block.
#define RGRID 256

__global__ __launch_bounds__(512) void gru_rec_kernel(
    const float* __restrict__ whh,   // [3072][1024] this layer
    const float* __restrict__ bhh,   // [3072]
    const u16*  __restrict__ gi,     // [T][B][3H] bf16, includes b_ih
    const float* __restrict__ h0,    // [B][H] this layer
    float* __restrict__ hbuf0, float* __restrict__ hbuf1,
    u16*  __restrict__ phi, u16* __restrict__ plo,   // next-layer planes or null
    float* __restrict__ seqout,                      // fp32 [B][T][H] or null
    float* __restrict__ hnout,                       // [B][H]
    unsigned* __restrict__ flags)                    // [4 domains][64 producers]
{
    const int tid  = threadIdx.x;
    const int lane = tid & 63;
    const int w    = tid >> 6;           // 8 waves
    const int ug   = blockIdx.x >> 2;    // 0..63
    const int bg   = blockIdx.x & 3;     // 0..3  (sync domain)
    const int u0   = ug * 16;
    const int b0   = bg * 8;

    unsigned* dom_flags = flags + bg * 64;     // this domain's 64 flags (256B)

    __shared__ __align__(16) float h_lds[8 * HD];        // 32 KB
    __shared__ __align__(16) float dsm[8 * 48 * 4];      // 6 KB partials
    __shared__ float bsh[48];

    // weights: wave w holds block-rows w*6..w*6+5; lane's K-slice = {q*256 + lane*4 + e}
    float wreg[6][16];
#pragma unroll
    for (int j = 0; j < 6; ++j) {
        int r = w * 6 + j;
        int g = r >> 4, uu = r & 15;
        const float* wp = whh + (size_t)(g * HD + u0 + uu) * HD;
#pragma unroll
        for (int q = 0; q < 4; ++q) {
            f32x4 v = *(const f32x4*)(wp + q * 256 + lane * 4);
            wreg[j][q * 4 + 0] = v[0]; wreg[j][q * 4 + 1] = v[1];
            wreg[j][q * 4 + 2] = v[2]; wreg[j][q * 4 + 3] = v[3];
        }
    }
    if (tid < 48) bsh[tid] = bhh[(tid >> 4) * HD + u0 + (tid & 15)];
    __syncthreads();

    const int gb = tid >> 4;    // gate-phase batch (tid<128)
    const int gu = tid & 15;    // gate-phase unit

    for (int t = 0; t < TT; ++t) {
        // ---- gi prefetch (independent of h; normal cached loads)
        unsigned gr0, gr1, gr2;
        if (tid < 128) {
            const u16* gp = gi + (size_t)(t * BB + b0 + gb) * H3 + u0 + gu;
            ld_u16_async(gr0, gp);
            ld_u16_async(gr1, gp + HD);
            ld_u16_async(gr2, gp + 2 * HD);
        }
        // ---- wave 0 polls this domain's 64 producer flags; others park at barrier
        if (t > 0 && w == 0) {
            const unsigned* fp = dom_flags + lane;
            unsigned v;
            do {
                asm volatile("global_load_dword %0, %1, off sc0 sc1" : "=v"(v) : "v"(fp));
                asm volatile("s_waitcnt vmcnt(0)" : "+v"(v));
            } while (!__all((int)(v >= (unsigned)t)));
        }
        __syncthreads();

        // ---- stage h(t) for our 8 batches into LDS (coherent loads)
        const float* hsrc = (t == 0) ? (h0 + b0 * HD)
                                     : (((t & 1) ? hbuf1 : hbuf0) + b0 * HD);
        f32x4 s0_, s1_, s2_, s3_;
        coh_load_f4(s0_, hsrc + (0 * 512 + tid) * 4);
        coh_load_f4(s1_, hsrc + (1 * 512 + tid) * 4);
        coh_load_f4(s2_, hsrc + (2 * 512 + tid) * 4);
        coh_load_f4(s3_, hsrc + (3 * 512 + tid) * 4);
        asm volatile("s_waitcnt vmcnt(0)" : "+v"(s0_), "+v"(s1_), "+v"(s2_), "+v"(s3_));
        *(f32x4*)&h_lds[(0 * 512 + tid) * 4] = s0_;
        *(f32x4*)&h_lds[(1 * 512 + tid) * 4] = s1_;
        *(f32x4*)&h_lds[(2 * 512 + tid) * 4] = s2_;
        *(f32x4*)&h_lds[(3 * 512 + tid) * 4] = s3_;
        __syncthreads();

        // ---- dot phase: 6 rows x 8 batches per wave, 16 K-elems per lane
#pragma unroll 2
        for (int b = 0; b < 8; ++b) {
            const float* hr = h_lds + b * HD;
            f32x4 h0v = *(const f32x4*)(hr + 0 * 256 + lane * 4);
            f32x4 h1v = *(const f32x4*)(hr + 1 * 256 + lane * 4);
            f32x4 h2v = *(const f32x4*)(hr + 2 * 256 + lane * 4);
            f32x4 h3v = *(const f32x4*)(hr + 3 * 256 + lane * 4);
#pragma unroll
            for (int j = 0; j < 6; ++j) {
                float a = 0.f;
#pragma unroll
                for (int e = 0; e < 4; ++e) {
                    a = fmaf(wreg[j][e],      h0v[e], a);
                    a = fmaf(wreg[j][4 + e],  h1v[e], a);
                    a = fmaf(wreg[j][8 + e],  h2v[e], a);
                    a = fmaf(wreg[j][12 + e], h3v[e], a);
                }
                a += __shfl_xor(a, 1);
                a += __shfl_xor(a, 2);
                a += __shfl_xor(a, 4);
                a += __shfl_xor(a, 8);
                if ((lane & 15) == 0)
                    dsm[(b * 48 + w * 6 + j) * 4 + (lane >> 4)] = a;
            }
        }
        __syncthreads();

        // ---- gate phase: 128 threads, one (b,u) each
        float* hdst = ((t + 1) & 1) ? hbuf1 : hbuf0;
        float hnew = 0.f;
        size_t orow = 0;
        if (tid < 128) {
            f32x4 p0 = *(const f32x4*)&dsm[(gb * 48 + 0 * 16 + gu) * 4];
            f32x4 p1 = *(const f32x4*)&dsm[(gb * 48 + 1 * 16 + gu) * 4];
            f32x4 p2 = *(const f32x4*)&dsm[(gb * 48 + 2 * 16 + gu) * 4];
            float dr = p0[0] + p0[1] + p0[2] + p0[3] + bsh[gu];
            float dz = p1[0] + p1[1] + p1[2] + p1[3] + bsh[16 + gu];
            float dn = p2[0] + p2[1] + p2[2] + p2[3] + bsh[32 + gu];
            float ir  = bf_bits2f((u16)gr0);
            float iz  = bf_bits2f((u16)gr1);
            float inn = bf_bits2f((u16)gr2);
            float hp = h_lds[gb * HD + u0 + gu];
            float r = 1.f / (1.f + expf(-(ir + dr)));
            float z = 1.f / (1.f + expf(-(iz + dz)));
            float nn = tanhf(inn + r * dn);
            hnew = (1.f - z) * nn + z * hp;
            int gidx = (b0 + gb) * HD + u0 + gu;
            coh_store_f32(hdst + gidx, hnew);          // the release payload
            orow = ((size_t)(b0 + gb) * TT + t) * HD + u0 + gu;
            if (t == TT - 1) hnout[gidx] = hnew;
            asm volatile("s_waitcnt vmcnt(0)" ::: "memory");  // h at IC
        }
        __syncthreads();   // all producers' h drained
        if (t < TT - 1 && tid == 0)
            coh_store_u32(dom_flags + ug, (unsigned)(t + 1));   // release
        // ---- off-critical-path output stores
        if (tid < 128) {
            if (seqout) {
                seqout[orow] = hnew;
            } else {
                u16 hb_ = f2bf_bits(hnew);
                phi[orow] = hb_;
                plo[orow] = f2bf_bits(hnew - bf_bits2f(hb_));
            }
        }
    }
}

// ---------------------------------------------------------------------------
extern "C" void kernel_launch(void* const* d_in, const int* in_sizes, int n_in,
                              void* d_out, int out_size, void* d_ws, size_t ws_size,
                              hipStream_t stream) {
    const float* x   = (const float*)d_in[0];
    const float* h0  = (const float*)d_in[1];
    const float* wih = (const float*)d_in[2];
    const float* whh = (const float*)d_in[3];
    const float* bih = (const float*)d_in[4];
    const float* bhh = (const float*)d_in[5];
    float* out = (float*)d_out;

    char* ws = (char*)d_ws;
    size_t off = 0;
    auto alloc = [&](size_t bytes) -> void* {
        void* p = ws + off;
        off += (bytes + 255) & ~(size_t)255;
        return p;
    };
    u16* gi   = (u16*)alloc((size_t)MTOT * H3 * 2);        // 96 MB
    u16* p0h  = (u16*)alloc((size_t)MTOT * HD * 2);        // 32 MB
    u16* p0l  = (u16*)alloc((size_t)MTOT * HD * 2);
    u16* p1h  = (u16*)alloc((size_t)MTOT * HD * 2);
    u16* p1l  = (u16*)alloc((size_t)MTOT * HD * 2);
    u16* wihb = (u16*)alloc((size_t)LL * H3 * HD * 2);     // 18 MB
    float* hb0 = (float*)alloc((size_t)BB * HD * 4);
    float* hb1 = (float*)alloc((size_t)BB * HD * 4);
    unsigned* flags = (unsigned*)alloc(LL * 4 * 64 * 4);   // [L][4 dom][64]

    hipMemsetAsync(flags, 0, LL * 4 * 64 * 4, stream);

    split_f32_kernel<<<2048, 256, 0, stream>>>(x, p0h, p0l, MTOT * HD / 4);
    tobf_kernel<<<2048, 256, 0, stream>>>(wih, wihb, LL * H3 * HD / 4);

    float* seqbase = out;                        // [B][T][H]
    float* hnbase  = out + (size_t)BB * TT * HD; // [L][B][H]

    for (int l = 0; l < LL; ++l) {
        const u16* ah = (l == 1) ? p1h : p0h;
        const u16* al = (l == 1) ? p1l : p0l;
        gemm2p_kernel<<<dim3(128 * 24), 256, 0, stream>>>(
            ah, al, wihb + (size_t)l * H3 * HD, bih + (size_t)l * H3, gi);

        u16* oh = (l == 0) ? p1h : p0h;
        u16* ol = (l == 0) ? p1l : p0l;
        gru_rec_kernel<<<RGRID, 512, 0, stream>>>(
            whh + (size_t)l * H3 * HD, bhh + (size_t)l * H3, gi,
            h0 + (size_t)l * BB * HD, hb0, hb1,
            (l < 2) ? oh : (u16*)nullptr, (l < 2) ? ol : (u16*)nullptr,
            (l == 2) ? seqbase : (float*)nullptr,
            hnbase + (size_t)l * BB * HD,
            flags + (size_t)l * 4 * 64);
    }
}

// Round 4
// 21213.397 us; speedup vs baseline: 2.1368x; 1.0189x over previous
//
#include <hip/hip_runtime.h>
#include <hip/hip_bf16.h>
#include <stdint.h>

// Problem constants
#define HD   1024
#define BB   32
#define TT   512
#define LL   3
#define H3   3072
#define MTOT (BB*TT)   // 16384

typedef unsigned short u16;
typedef short bf16x8 __attribute__((ext_vector_type(8)));
typedef float f32x4 __attribute__((ext_vector_type(4)));

__device__ __forceinline__ u16 f2bf_bits(float f) {
    __hip_bfloat16 h = __float2bfloat16(f);   // RNE
    return __builtin_bit_cast(u16, h);
}
__device__ __forceinline__ float bf_bits2f(u16 b) {
    return __bfloat162float(__builtin_bit_cast(__hip_bfloat16, b));
}

// ---- coherent (IC-level) loads: sc0 sc1 bypasses L1 and per-XCD L2.
__device__ __forceinline__ void coh_load_f4(f32x4& d, const float* p) {
    asm volatile("global_load_dwordx4 %0, %1, off sc0 sc1" : "=v"(d) : "v"(p));
}
__device__ __forceinline__ void ld_u16_async(unsigned& d, const u16* p) {
    asm volatile("global_load_ushort %0, %1, off" : "=v"(d) : "v"(p));
}

// ---------------------------------------------------------------------------
// Split fp32 -> (hi, lo) bf16 planes
__global__ void split_f32_kernel(const float* __restrict__ in,
                                 u16* __restrict__ hi, u16* __restrict__ lo, int n4) {
    int i = blockIdx.x * blockDim.x + threadIdx.x;
    int stride = gridDim.x * blockDim.x;
    for (; i < n4; i += stride) {
        float4 v = ((const float4*)in)[i];
        ushort4 h, l;
        float f;
        f = v.x; h.x = f2bf_bits(f); l.x = f2bf_bits(f - bf_bits2f(h.x));
        f = v.y; h.y = f2bf_bits(f); l.y = f2bf_bits(f - bf_bits2f(h.y));
        f = v.z; h.z = f2bf_bits(f); l.z = f2bf_bits(f - bf_bits2f(h.z));
        f = v.w; h.w = f2bf_bits(f); l.w = f2bf_bits(f - bf_bits2f(h.w));
        ((ushort4*)hi)[i] = h;
        ((ushort4*)lo)[i] = l;
    }
}

// fp32 -> bf16 (hi only)
__global__ void tobf_kernel(const float* __restrict__ in, u16* __restrict__ out, int n4) {
    int i = blockIdx.x * blockDim.x + threadIdx.x;
    int stride = gridDim.x * blockDim.x;
    for (; i < n4; i += stride) {
        float4 v = ((const float4*)in)[i];
        ushort4 h;
        h.x = f2bf_bits(v.x); h.y = f2bf_bits(v.y);
        h.z = f2bf_bits(v.z); h.w = f2bf_bits(v.w);
        ((ushort4*)out)[i] = h;
    }
}

// ---------------------------------------------------------------------------
// 2-pass split-A bf16 MFMA GEMM:  C[t*32+b][n] = sum_k (Ahi+Alo)[b*512+t][k]*W[n][k] + bias[n]
#define BM 128
#define BN 128
#define BK 32
#define LDSROW 40   // 32 data bf16 + 8 pad

__global__ __launch_bounds__(256) void gemm2p_kernel(
    const u16* __restrict__ Ahi, const u16* __restrict__ Alo,  // [M][1024]
    const u16* __restrict__ Wn,                                 // [3072][1024]
    const float* __restrict__ bias,                             // [3072]
    u16* __restrict__ Cout)                                     // [T*B perm][3072]
{
    __shared__ u16 sAh[BM * LDSROW];
    __shared__ u16 sAl[BM * LDSROW];
    __shared__ u16 sB [BN * LDSROW];

    const int tid  = threadIdx.x;
    const int lane = tid & 63;
    const int w    = tid >> 6;        // 4 waves
    const int wr   = w >> 1, wc = w & 1;
    const int fr   = lane & 15;
    const int kg   = lane >> 4;

    const int bm = blockIdx.x & 127;         // M/BM = 128
    const int bn = blockIdx.x >> 7;          // N/BN = 24
    const int bmBase = bm * BM;
    const int bnBase = bn * BN;

    f32x4 acc[4][4] = {};

    for (int kt = 0; kt < 1024; kt += BK) {
        uint4 ra[2], rl[2], rb[2];
#pragma unroll
        for (int it = 0; it < 2; ++it) {
            int c = it * 256 + tid;
            int row = c >> 2, seg = c & 3;
            size_t ga = (size_t)(bmBase + row) * 1024 + kt + seg * 8;
            ra[it] = *(const uint4*)(Ahi + ga);
            rl[it] = *(const uint4*)(Alo + ga);
            size_t gb = (size_t)(bnBase + row) * 1024 + kt + seg * 8;
            rb[it] = *(const uint4*)(Wn + gb);
        }
        __syncthreads();
#pragma unroll
        for (int it = 0; it < 2; ++it) {
            int c = it * 256 + tid;
            int row = c >> 2, seg = c & 3;
            int lo = row * LDSROW + seg * 8;
            *(uint4*)(sAh + lo) = ra[it];
            *(uint4*)(sAl + lo) = rl[it];
            *(uint4*)(sB  + lo) = rb[it];
        }
        __syncthreads();

        bf16x8 fah[4], fal[4], fb[4];
#pragma unroll
        for (int mi = 0; mi < 4; ++mi) {
            int r = wr * 64 + mi * 16 + fr;
            fah[mi] = *(const bf16x8*)(sAh + r * LDSROW + kg * 8);
            fal[mi] = *(const bf16x8*)(sAl + r * LDSROW + kg * 8);
        }
#pragma unroll
        for (int ni = 0; ni < 4; ++ni) {
            int r = wc * 64 + ni * 16 + fr;
            fb[ni] = *(const bf16x8*)(sB + r * LDSROW + kg * 8);
        }
#pragma unroll
        for (int mi = 0; mi < 4; ++mi)
#pragma unroll
            for (int ni = 0; ni < 4; ++ni) {
                acc[mi][ni] = __builtin_amdgcn_mfma_f32_16x16x32_bf16(fah[mi], fb[ni], acc[mi][ni], 0, 0, 0);
                acc[mi][ni] = __builtin_amdgcn_mfma_f32_16x16x32_bf16(fal[mi], fb[ni], acc[mi][ni], 0, 0, 0);
            }
    }

#pragma unroll
    for (int mi = 0; mi < 4; ++mi)
#pragma unroll
        for (int ni = 0; ni < 4; ++ni) {
            int n = bnBase + wc * 64 + ni * 16 + fr;
            float bv = bias[n];
#pragma unroll
            for (int r = 0; r < 4; ++r) {
                int m = bmBase + wr * 64 + mi * 16 + kg * 4 + r;
                int b_ = m >> 9, t_ = m & 511;           // m = b*512 + t
                Cout[(size_t)(t_ * BB + b_) * H3 + n] = f2bf_bits(acc[mi][ni][r] + bv);
            }
        }
}

// ---------------------------------------------------------------------------
// Persistent recurrent kernel: 256 blocks (64 unit-groups x 4 batch-groups) x
// 512 threads. h exchange + flags via device-scope atomics (performed at IC,
// acked at IC -> no write-through-to-memory latency on the release path).
#define RGRID 256

__global__ __launch_bounds__(512) void gru_rec_kernel(
    const float* __restrict__ whh,   // [3072][1024] this layer
    const float* __restrict__ bhh,   // [3072]
    const u16*  __restrict__ gi,     // [T][B][3H] bf16, includes b_ih
    const float* __restrict__ h0,    // [B][H] this layer
    float* __restrict__ hbuf0, float* __restrict__ hbuf1,
    u16*  __restrict__ phi, u16* __restrict__ plo,   // next-layer planes or null
    float* __restrict__ seqout,                      // fp32 [B][T][H] or null
    float* __restrict__ hnout,                       // [B][H]
    unsigned* __restrict__ flags)                    // [4 domains][64 producers]
{
    const int tid  = threadIdx.x;
    const int lane = tid & 63;
    const int w    = tid >> 6;           // 8 waves
    const int ug   = blockIdx.x >> 2;    // 0..63
    const int bg   = blockIdx.x & 3;     // 0..3  (sync domain)
    const int u0   = ug * 16;
    const int b0   = bg * 8;

    unsigned* dom_flags = flags + bg * 64;     // this domain's 64 flags (256B)

    __shared__ __align__(16) float h_lds[8 * HD];        // 32 KB
    __shared__ __align__(16) float dsm[8 * 48 * 4];      // 6 KB partials
    __shared__ float bsh[48];

    // weights: wave w holds block-rows w*6..w*6+5; lane's K-slice = {q*256 + lane*4 + e}
    float wreg[6][16];
#pragma unroll
    for (int j = 0; j < 6; ++j) {
        int r = w * 6 + j;
        int g = r >> 4, uu = r & 15;
        const float* wp = whh + (size_t)(g * HD + u0 + uu) * HD;
#pragma unroll
        for (int q = 0; q < 4; ++q) {
            f32x4 v = *(const f32x4*)(wp + q * 256 + lane * 4);
            wreg[j][q * 4 + 0] = v[0]; wreg[j][q * 4 + 1] = v[1];
            wreg[j][q * 4 + 2] = v[2]; wreg[j][q * 4 + 3] = v[3];
        }
    }
    if (tid < 48) bsh[tid] = bhh[(tid >> 4) * HD + u0 + (tid & 15)];
    __syncthreads();

    const int gb = tid >> 4;    // gate-phase batch (tid<128)
    const int gu = tid & 15;    // gate-phase unit

    // gi prefetch for t=0 (pipelined one step ahead thereafter)
    unsigned gr0, gr1, gr2;
    if (tid < 128) {
        const u16* gp = gi + (size_t)(0 * BB + b0 + gb) * H3 + u0 + gu;
        ld_u16_async(gr0, gp);
        ld_u16_async(gr1, gp + HD);
        ld_u16_async(gr2, gp + 2 * HD);
    }

    for (int t = 0; t < TT; ++t) {
        // ---- wave 0 polls this domain's 64 producer flags; others park at barrier
        if (t > 0 && w == 0) {
            const unsigned* fp = dom_flags + lane;
            unsigned v;
            do {
                asm volatile("global_load_dword %0, %1, off sc0 sc1" : "=v"(v) : "v"(fp));
                asm volatile("s_waitcnt vmcnt(0)" : "+v"(v));
            } while (!__all((int)(v >= (unsigned)t)));
        }
        __syncthreads();

        // ---- stage h(t) for our 8 batches into LDS (IC-coherent loads)
        const float* hsrc = (t == 0) ? (h0 + b0 * HD)
                                     : (((t & 1) ? hbuf1 : hbuf0) + b0 * HD);
        f32x4 s0_, s1_, s2_, s3_;
        coh_load_f4(s0_, hsrc + (0 * 512 + tid) * 4);
        coh_load_f4(s1_, hsrc + (1 * 512 + tid) * 4);
        coh_load_f4(s2_, hsrc + (2 * 512 + tid) * 4);
        coh_load_f4(s3_, hsrc + (3 * 512 + tid) * 4);
        asm volatile("s_waitcnt vmcnt(0)" : "+v"(s0_), "+v"(s1_), "+v"(s2_), "+v"(s3_));
        *(f32x4*)&h_lds[(0 * 512 + tid) * 4] = s0_;
        *(f32x4*)&h_lds[(1 * 512 + tid) * 4] = s1_;
        *(f32x4*)&h_lds[(2 * 512 + tid) * 4] = s2_;
        *(f32x4*)&h_lds[(3 * 512 + tid) * 4] = s3_;
        __syncthreads();

        // ---- dot phase: 6 rows x 8 batches per wave, 16 K-elems per lane
#pragma unroll 2
        for (int b = 0; b < 8; ++b) {
            const float* hr = h_lds + b * HD;
            f32x4 h0v = *(const f32x4*)(hr + 0 * 256 + lane * 4);
            f32x4 h1v = *(const f32x4*)(hr + 1 * 256 + lane * 4);
            f32x4 h2v = *(const f32x4*)(hr + 2 * 256 + lane * 4);
            f32x4 h3v = *(const f32x4*)(hr + 3 * 256 + lane * 4);
#pragma unroll
            for (int j = 0; j < 6; ++j) {
                float a = 0.f;
#pragma unroll
                for (int e = 0; e < 4; ++e) {
                    a = fmaf(wreg[j][e],      h0v[e], a);
                    a = fmaf(wreg[j][4 + e],  h1v[e], a);
                    a = fmaf(wreg[j][8 + e],  h2v[e], a);
                    a = fmaf(wreg[j][12 + e], h3v[e], a);
                }
                a += __shfl_xor(a, 1);
                a += __shfl_xor(a, 2);
                a += __shfl_xor(a, 4);
                a += __shfl_xor(a, 8);
                if ((lane & 15) == 0)
                    dsm[(b * 48 + w * 6 + j) * 4 + (lane >> 4)] = a;
            }
        }
        __syncthreads();

        // ---- gate phase: 128 threads, one (b,u) each
        float* hdst = ((t + 1) & 1) ? hbuf1 : hbuf0;
        float hnew = 0.f;
        int gidx = 0;
        size_t orow = 0;
        if (tid < 128) {
            f32x4 p0 = *(const f32x4*)&dsm[(gb * 48 + 0 * 16 + gu) * 4];
            f32x4 p1 = *(const f32x4*)&dsm[(gb * 48 + 1 * 16 + gu) * 4];
            f32x4 p2 = *(const f32x4*)&dsm[(gb * 48 + 2 * 16 + gu) * 4];
            float dr = p0[0] + p0[1] + p0[2] + p0[3] + bsh[gu];
            float dz = p1[0] + p1[1] + p1[2] + p1[3] + bsh[16 + gu];
            float dn = p2[0] + p2[1] + p2[2] + p2[3] + bsh[32 + gu];
            float ir  = bf_bits2f((u16)gr0);
            float iz  = bf_bits2f((u16)gr1);
            float inn = bf_bits2f((u16)gr2);
            float hp = h_lds[gb * HD + u0 + gu];
            float r = 1.f / (1.f + expf(-(ir + dr)));
            float z = 1.f / (1.f + expf(-(iz + dz)));
            float nn = tanhf(inn + r * dn);
            hnew = (1.f - z) * nn + z * hp;
            gidx = (b0 + gb) * HD + u0 + gu;
            orow = ((size_t)(b0 + gb) * TT + t) * HD + u0 + gu;
            // release payload: device-scope atomic, performed+acked at IC
            (void)__hip_atomic_exchange(hdst + gidx, hnew,
                                        __ATOMIC_RELAXED, __HIP_MEMORY_SCOPE_AGENT);
        }
        __syncthreads();   // implicit vmcnt(0): all producers' h atomics acked
        if (t < TT - 1 && tid == 0)
            (void)__hip_atomic_exchange(dom_flags + ug, (unsigned)(t + 1),
                                        __ATOMIC_RELAXED, __HIP_MEMORY_SCOPE_AGENT);
        // ---- off-critical-path: next-step gi prefetch + output stores
        if (t + 1 < TT && tid < 128) {
            const u16* gp = gi + (size_t)((t + 1) * BB + b0 + gb) * H3 + u0 + gu;
            ld_u16_async(gr0, gp);
            ld_u16_async(gr1, gp + HD);
            ld_u16_async(gr2, gp + 2 * HD);
        }
        if (tid < 128) {
            if (seqout) {
                seqout[orow] = hnew;
            } else {
                u16 hb_ = f2bf_bits(hnew);
                phi[orow] = hb_;
                plo[orow] = f2bf_bits(hnew - bf_bits2f(hb_));
            }
            if (t == TT - 1) hnout[gidx] = hnew;
        }
    }
}

// ---------------------------------------------------------------------------
extern "C" void kernel_launch(void* const* d_in, const int* in_sizes, int n_in,
                              void* d_out, int out_size, void* d_ws, size_t ws_size,
                              hipStream_t stream) {
    const float* x   = (const float*)d_in[0];
    const float* h0  = (const float*)d_in[1];
    const float* wih = (const float*)d_in[2];
    const float* whh = (const float*)d_in[3];
    const float* bih = (const float*)d_in[4];
    const float* bhh = (const float*)d_in[5];
    float* out = (float*)d_out;

    char* ws = (char*)d_ws;
    size_t off = 0;
    auto alloc = [&](size_t bytes) -> void* {
        void* p = ws + off;
        off += (bytes + 255) & ~(size_t)255;
        return p;
    };
    u16* gi   = (u16*)alloc((size_t)MTOT * H3 * 2);        // 96 MB
    u16* p0h  = (u16*)alloc((size_t)MTOT * HD * 2);        // 32 MB
    u16* p0l  = (u16*)alloc((size_t)MTOT * HD * 2);
    u16* p1h  = (u16*)alloc((size_t)MTOT * HD * 2);
    u16* p1l  = (u16*)alloc((size_t)MTOT * HD * 2);
    u16* wihb = (u16*)alloc((size_t)LL * H3 * HD * 2);     // 18 MB
    float* hb0 = (float*)alloc((size_t)BB * HD * 4);
    float* hb1 = (float*)alloc((size_t)BB * HD * 4);
    unsigned* flags = (unsigned*)alloc(LL * 4 * 64 * 4);   // [L][4 dom][64]

    hipMemsetAsync(flags, 0, LL * 4 * 64 * 4, stream);

    split_f32_kernel<<<2048, 256, 0, stream>>>(x, p0h, p0l, MTOT * HD / 4);
    tobf_kernel<<<2048, 256, 0, stream>>>(wih, wihb, LL * H3 * HD / 4);

    float* seqbase = out;                        // [B][T][H]
    float* hnbase  = out + (size_t)BB * TT * HD; // [L][B][H]

    for (int l = 0; l < LL; ++l) {
        const u16* ah = (l == 1) ? p1h : p0h;
        const u16* al = (l == 1) ? p1l : p0l;
        gemm2p_kernel<<<dim3(128 * 24), 256, 0, stream>>>(
            ah, al, wihb + (size_t)l * H3 * HD, bih + (size_t)l * H3, gi);

        u16* oh = (l == 0) ? p1h : p0h;
        u16* ol = (l == 0) ? p1l : p0l;
        gru_rec_kernel<<<RGRID, 512, 0, stream>>>(
            whh + (size_t)l * H3 * HD, bhh + (size_t)l * H3, gi,
            h0 + (size_t)l * BB * HD, hb0, hb1,
            (l < 2) ? oh : (u16*)nullptr, (l < 2) ? ol : (u16*)nullptr,
            (l == 2) ? seqbase : (float*)nullptr,
            hnbase + (size_t)l * BB * HD,
            flags + (size_t)l * 4 * 64);
    }
}